// Round 1
// 785.560 us; speedup vs baseline: 1.7364x; 1.7364x over previous
//
#include <hip/hip_runtime.h>
#include <math.h>

#define BB  2
#define SS  4096
#define EE  1024
#define HH  16
#define DD  64
#define WW  256
#define NCC 16   // SS / WW
#define MTOT (BB*SS)   // 8192

typedef __attribute__((ext_vector_type(4))) float f32x4;
typedef __attribute__((ext_vector_type(8))) short bf16x8;

// ---------------------------------------------------------------------------
// async global->LDS, 16B per lane. LDS dest must be wave-uniform base
// (+lane*16 is applied by HW); global src is per-lane.
// ---------------------------------------------------------------------------
__device__ __forceinline__ void gl_lds16(const void* g, void* l) {
  __builtin_amdgcn_global_load_lds(
      (const __attribute__((address_space(1))) unsigned int*)g,
      (__attribute__((address_space(3))) unsigned int*)l,
      16, 0, 0);
}

// ---------------------------------------------------------------------------
// Split fp32 x into bf16 hi (truncated) + bf16 lo (RNE of residual).
// x ~= hi + lo to ~2^-17 relative. Vectorized float4 per thread.
// ---------------------------------------------------------------------------
__global__ __launch_bounds__(256) void split_kernel(
    const float* __restrict__ x, unsigned short* __restrict__ hi,
    unsigned short* __restrict__ lo)
{
  const size_t i = (size_t)blockIdx.x * 256 + threadIdx.x;
  const float4 v = ((const float4*)x)[i];
  float f[4] = {v.x, v.y, v.z, v.w};
  unsigned short h[4], l[4];
  #pragma unroll
  for (int j = 0; j < 4; ++j) {
    unsigned u  = __float_as_uint(f[j]);
    unsigned uh = u & 0xFFFF0000u;
    h[j] = (unsigned short)(uh >> 16);
    float r = f[j] - __uint_as_float(uh);   // exact in fp32
    unsigned ur = __float_as_uint(r);
    ur += ((ur >> 16) & 1u) + 0x7FFFu;      // RNE to bf16
    l[j] = (unsigned short)(ur >> 16);
  }
  *(ushort4*)&hi[4*i] = make_ushort4(h[0], h[1], h[2], h[3]);
  *(ushort4*)&lo[4*i] = make_ushort4(l[0], l[1], l[2], l[3]);
}

// ---------------------------------------------------------------------------
// bf16x3-split MFMA projection GEMM: C = (A @ W^T + b) * scale, fp32-accurate.
// C ~= Ah*Bh + Ah*Bl + Al*Bh  (fp32 accumulation in MFMA).
// Tile 128x128, BK=32, 256 threads = 4 waves (2x2), 4x4 16x16 frags/wave.
// LDS k-plane layout: byte(row,kc) = (row>>3)*512 + kc*128 + (row&7)*16
//   -> bank index carries row[2:0]: fragment ds_read_b128 is conflict-free,
//      and global_load_lds dest stays linear (chunk q at byte q*16).
// ---------------------------------------------------------------------------
struct ProjArgs {
  const unsigned short* Wh;
  const unsigned short* Wl;
  const float* bias;
  float* out;
  float scale;
};

__global__ __launch_bounds__(256) void mfma_proj(
    const unsigned short* __restrict__ Ahi,
    const unsigned short* __restrict__ Alo,
    ProjArgs p0, ProjArgs p1, ProjArgs p2)
{
  __shared__ __align__(16) unsigned short lds[4][4096];  // Ah, Al, Bh, Bl (8KB each)
  const int tid  = threadIdx.x;
  const int lane = tid & 63;
  const int wid  = tid >> 6;
  const int wr   = wid >> 1, wc = wid & 1;
  const int m0   = blockIdx.x * 128, n0 = blockIdx.y * 128;
  const ProjArgs P = (blockIdx.z == 0) ? p0 : ((blockIdx.z == 1) ? p1 : p2);

  // staging: chunk q (16B) holds logical (row = ((q>>5)<<3)|(q&7), kc = (q>>3)&3)
  const int q0 = tid, q1 = 256 + tid;
  const int row0 = ((q0 >> 5) << 3) | (q0 & 7), kc0 = (q0 >> 3) & 3;
  const int row1 = ((q1 >> 5) << 3) | (q1 & 7), kc1 = (q1 >> 3) & 3;

  const size_t aoff0 = (size_t)(m0 + row0) * 2048 + (size_t)(kc0 * 16);
  const size_t aoff1 = (size_t)(m0 + row1) * 2048 + (size_t)(kc1 * 16);
  const size_t boff0 = (size_t)(n0 + row0) * 2048 + (size_t)(kc0 * 16);
  const size_t boff1 = (size_t)(n0 + row1) * 2048 + (size_t)(kc1 * 16);

  const int dst0 = (wid * 64) * 16;          // wave-uniform LDS byte base, round 0
  const int dst1 = (256 + wid * 64) * 16;    // round 1

  const char* gAh = (const char*)Ahi;
  const char* gAl = (const char*)Alo;
  const char* gBh = (const char*)P.Wh;
  const char* gBl = (const char*)P.Wl;

  // fragment LDS byte offsets (16x16x32 bf16: lane -> row=(l&15), k-chunk=(l>>4))
  const int fr = lane & 15;
  const int kc = lane >> 4;
  int a_o[4], b_o[4];
  #pragma unroll
  for (int f = 0; f < 4; ++f) {
    int r = wr * 64 + f * 16 + fr;
    a_o[f] = ((r >> 3) << 9) | (kc << 7) | ((r & 7) << 4);
    r = wc * 64 + f * 16 + fr;
    b_o[f] = ((r >> 3) << 9) | (kc << 7) | ((r & 7) << 4);
  }

  f32x4 acc[4][4];
  #pragma unroll
  for (int i = 0; i < 4; ++i)
    #pragma unroll
    for (int j = 0; j < 4; ++j) acc[i][j] = (f32x4){0.f, 0.f, 0.f, 0.f};

  char* L0 = (char*)&lds[0][0];
  char* L1 = (char*)&lds[1][0];
  char* L2 = (char*)&lds[2][0];
  char* L3 = (char*)&lds[3][0];

  for (int ks = 0; ks < 32; ++ks) {
    const size_t kb = (size_t)ks * 64;   // 32 bf16 = 64B per row per step
    __syncthreads();                     // previous compute done before overwrite
    gl_lds16(gAh + aoff0 + kb, L0 + dst0);
    gl_lds16(gAh + aoff1 + kb, L0 + dst1);
    gl_lds16(gAl + aoff0 + kb, L1 + dst0);
    gl_lds16(gAl + aoff1 + kb, L1 + dst1);
    gl_lds16(gBh + boff0 + kb, L2 + dst0);
    gl_lds16(gBh + boff1 + kb, L2 + dst1);
    gl_lds16(gBl + boff0 + kb, L3 + dst0);
    gl_lds16(gBl + boff1 + kb, L3 + dst1);
    __syncthreads();                     // drains vmcnt: LDS tiles ready

    bf16x8 ah[4], al[4], bh[4], bl[4];
    #pragma unroll
    for (int f = 0; f < 4; ++f) {
      ah[f] = *(const bf16x8*)(L0 + a_o[f]);
      al[f] = *(const bf16x8*)(L1 + a_o[f]);
      bh[f] = *(const bf16x8*)(L2 + b_o[f]);
      bl[f] = *(const bf16x8*)(L3 + b_o[f]);
    }
    // three split passes, each 16 independent MFMAs (hides MFMA latency)
    #pragma unroll
    for (int i = 0; i < 4; ++i)
      #pragma unroll
      for (int j = 0; j < 4; ++j)
        acc[i][j] = __builtin_amdgcn_mfma_f32_16x16x32_bf16(ah[i], bh[j], acc[i][j], 0, 0, 0);
    #pragma unroll
    for (int i = 0; i < 4; ++i)
      #pragma unroll
      for (int j = 0; j < 4; ++j)
        acc[i][j] = __builtin_amdgcn_mfma_f32_16x16x32_bf16(ah[i], bl[j], acc[i][j], 0, 0, 0);
    #pragma unroll
    for (int i = 0; i < 4; ++i)
      #pragma unroll
      for (int j = 0; j < 4; ++j)
        acc[i][j] = __builtin_amdgcn_mfma_f32_16x16x32_bf16(al[i], bh[j], acc[i][j], 0, 0, 0);
  }

  // epilogue: C/D layout col = lane&15, row = (lane>>4)*4 + reg
  const int r4 = (lane >> 4) << 2;
  #pragma unroll
  for (int j = 0; j < 4; ++j) {
    const int col = n0 + wc * 64 + j * 16 + fr;
    const float bv = P.bias[col];
    #pragma unroll
    for (int i = 0; i < 4; ++i) {
      const int rrow = m0 + wr * 64 + i * 16 + r4;
      #pragma unroll
      for (int v = 0; v < 4; ++v)
        P.out[(size_t)(rrow + v) * EE + col] = (acc[i][j][v] + bv) * P.scale;
    }
  }
}

// ---------------------------------------------------------------------------
// Fused no-overlap sliding-chunk attention (unchanged this round).
// Block = one (chunk c, head h, batch b). 256 threads = 256 query rows.
// ---------------------------------------------------------------------------
__global__ __launch_bounds__(256) void attn_kernel(
    const float* __restrict__ Q, const float* __restrict__ K,
    const float* __restrict__ V, float* __restrict__ O)
{
    __shared__ float Ks[32][64];
    __shared__ float Vs[32][64];
    const int c = blockIdx.x, h = blockIdx.y, b = blockIdx.z;
    const int x = threadIdx.x;
    const size_t row = (size_t)(b * NCC + c) * WW + x;

    float qr[DD];
    {
        const float* qp = Q + row * EE + h * DD;
        #pragma unroll
        for (int i = 0; i < DD/4; ++i) {
            float4 t4 = *(const float4*)(qp + 4*i);
            qr[4*i+0]=t4.x; qr[4*i+1]=t4.y; qr[4*i+2]=t4.z; qr[4*i+3]=t4.w;
        }
    }
    float o[DD];
    #pragma unroll
    for (int i = 0; i < DD; ++i) o[i] = 0.f;

    const int nz = (c == 0) ? x : ((c == NCC-1) ? (WW-1-x) : 0);
    float m = (nz > 0) ? 0.f : -1e30f;
    float l = (float)nz;

    const int kk_beg = (c == 0)      ? WW   : 0;
    const int kk_end = (c == NCC-1)  ? 2*WW : 3*WW;
    const size_t keybase = ((size_t)((b * NCC + c) * WW) - WW) * EE + (size_t)h * DD;

    const int lr = threadIdx.x >> 3;
    const int lc = (threadIdx.x & 7) << 3;

    for (int kt = kk_beg; kt < kk_end; kt += 32) {
        const float* kp = K + keybase + (size_t)(kt + lr) * EE + lc;
        const float* vp = V + keybase + (size_t)(kt + lr) * EE + lc;
        float4 k0 = *(const float4*)(kp);
        float4 k1 = *(const float4*)(kp + 4);
        float4 v0 = *(const float4*)(vp);
        float4 v1 = *(const float4*)(vp + 4);
        __syncthreads();
        *(float4*)&Ks[lr][lc]   = k0; *(float4*)&Ks[lr][lc+4] = k1;
        *(float4*)&Vs[lr][lc]   = v0; *(float4*)&Vs[lr][lc+4] = v1;
        __syncthreads();

        #pragma unroll
        for (int half = 0; half < 2; ++half) {
            float s[16];
            #pragma unroll
            for (int j = 0; j < 16; ++j) {
                const int jj = half*16 + j;
                float a = 0.f;
                #pragma unroll
                for (int d4 = 0; d4 < DD/4; ++d4) {
                    float4 kd = *(const float4*)&Ks[jj][4*d4];
                    a += qr[4*d4+0]*kd.x + qr[4*d4+1]*kd.y
                       + qr[4*d4+2]*kd.z + qr[4*d4+3]*kd.w;
                }
                s[j] = a;
            }
            float tmax = s[0];
            #pragma unroll
            for (int j = 1; j < 16; ++j) tmax = fmaxf(tmax, s[j]);
            if (tmax > m) {
                const float sc = __expf(m - tmax);
                l *= sc;
                #pragma unroll
                for (int i = 0; i < DD; ++i) o[i] *= sc;
                m = tmax;
            }
            #pragma unroll
            for (int j = 0; j < 16; ++j) {
                const int jj = half*16 + j;
                const float wgt = __expf(s[j] - m);
                l += wgt;
                #pragma unroll
                for (int d4 = 0; d4 < DD/4; ++d4) {
                    float4 vd = *(const float4*)&Vs[jj][4*d4];
                    o[4*d4+0] += wgt*vd.x; o[4*d4+1] += wgt*vd.y;
                    o[4*d4+2] += wgt*vd.z; o[4*d4+3] += wgt*vd.w;
                }
            }
        }
    }

    const float inv = 1.0f / l;
    float* op = O + row * EE + h * DD;
    #pragma unroll
    for (int i = 0; i < DD/4; ++i) {
        float4 r;
        r.x = o[4*i+0]*inv; r.y = o[4*i+1]*inv;
        r.z = o[4*i+2]*inv; r.w = o[4*i+3]*inv;
        *(float4*)(op + 4*i) = r;
    }
}

extern "C" void kernel_launch(void* const* d_in, const int* in_sizes, int n_in,
                              void* d_out, int out_size, void* d_ws, size_t ws_size,
                              hipStream_t stream) {
    const float* hs = (const float*)d_in[0];
    const float* Wq = (const float*)d_in[1];
    const float* bq = (const float*)d_in[2];
    const float* Wk = (const float*)d_in[3];
    const float* bk = (const float*)d_in[4];
    const float* Wv = (const float*)d_in[5];
    const float* bv = (const float*)d_in[6];
    float* out = (float*)d_out;

    const size_t mat  = (size_t)MTOT * EE;   // 8388608
    const size_t wmat = (size_t)EE * EE;     // 1048576

    float* qb = (float*)d_ws;
    float* kb = qb + mat;
    float* vb = kb + mat;
    unsigned short* Ahi = (unsigned short*)(vb + mat);
    unsigned short* Alo = Ahi + mat;
    unsigned short* Wqh = Alo + mat;
    unsigned short* Wql = Wqh + wmat;
    unsigned short* Wkh = Wql + wmat;
    unsigned short* Wkl = Wkh + wmat;
    unsigned short* Wvh = Wkl + wmat;
    unsigned short* Wvl = Wvh + wmat;
    // total ws: 96MB (qkv) + 32MB (A hi/lo) + 12MB (W hi/lo) = 140MB

    split_kernel<<<(mat/4)/256,  256, 0, stream>>>(hs, Ahi, Alo);
    split_kernel<<<(wmat/4)/256, 256, 0, stream>>>(Wq, Wqh, Wql);
    split_kernel<<<(wmat/4)/256, 256, 0, stream>>>(Wk, Wkh, Wkl);
    split_kernel<<<(wmat/4)/256, 256, 0, stream>>>(Wv, Wvh, Wvl);

    ProjArgs pq{Wqh, Wql, bq, qb, 0.125f};   // 1/sqrt(64)
    ProjArgs pk{Wkh, Wkl, bk, kb, 1.0f};
    ProjArgs pv{Wvh, Wvl, bv, vb, 1.0f};
    dim3 g(MTOT/128, EE/128, 3);
    mfma_proj<<<g, 256, 0, stream>>>(Ahi, Alo, pq, pk, pv);

    dim3 ga(NCC, HH, BB);
    attn_kernel<<<ga, 256, 0, stream>>>(qb, kb, vb, out);
}

// Round 3
// 350.354 us; speedup vs baseline: 3.8933x; 2.2422x over previous
//
#include <hip/hip_runtime.h>
#include <math.h>

#define BB  2
#define SS  4096
#define EE  1024
#define HH  16
#define DD  64
#define WW  256
#define NCC 16   // SS / WW
#define MTOT (BB*SS)   // 8192

typedef __attribute__((ext_vector_type(4))) float f32x4;
typedef __attribute__((ext_vector_type(8))) short bf16x8;

// ---------------------------------------------------------------------------
// async global->LDS, 16B per lane. LDS dest must be wave-uniform base
// (+lane*16 is applied by HW); global src is per-lane.
// ---------------------------------------------------------------------------
__device__ __forceinline__ void gl_lds16(const void* g, void* l) {
  __builtin_amdgcn_global_load_lds(
      (const __attribute__((address_space(1))) unsigned int*)g,
      (__attribute__((address_space(3))) unsigned int*)l,
      16, 0, 0);
}

__device__ __forceinline__ unsigned bf16rne(float f) {
  unsigned u = __float_as_uint(f);
  return (u + (((u >> 16) & 1u) + 0x7fffu)) >> 16;
}

__device__ __forceinline__ unsigned long long pack64(unsigned a, unsigned b,
                                                     unsigned c2, unsigned d) {
  return (unsigned long long)(a | (b << 16)) |
         ((unsigned long long)(c2 | (d << 16)) << 32);
}

// ---------------------------------------------------------------------------
// Split fp32 x into bf16 hi (truncated) + bf16 lo (RNE of residual).
// ---------------------------------------------------------------------------
__global__ __launch_bounds__(256) void split_kernel(
    const float* __restrict__ x, unsigned short* __restrict__ hi,
    unsigned short* __restrict__ lo)
{
  const size_t i = (size_t)blockIdx.x * 256 + threadIdx.x;
  const float4 v = ((const float4*)x)[i];
  float f[4] = {v.x, v.y, v.z, v.w};
  unsigned short h[4], l[4];
  #pragma unroll
  for (int j = 0; j < 4; ++j) {
    unsigned u  = __float_as_uint(f[j]);
    unsigned uh = u & 0xFFFF0000u;
    h[j] = (unsigned short)(uh >> 16);
    float r = f[j] - __uint_as_float(uh);
    unsigned ur = __float_as_uint(r);
    ur += ((ur >> 16) & 1u) + 0x7FFFu;
    l[j] = (unsigned short)(ur >> 16);
  }
  *(ushort4*)&hi[4*i] = make_ushort4(h[0], h[1], h[2], h[3]);
  *(ushort4*)&lo[4*i] = make_ushort4(l[0], l[1], l[2], l[3]);
}

// ---------------------------------------------------------------------------
// bf16x3-split MFMA projection GEMM: out = (A @ W^T + b) * scale.
// Output stored as split bf16 hi/lo pair (exact decomposition of the fp32
// result) so the attention kernel consumes MFMA-ready operands directly.
// ---------------------------------------------------------------------------
struct ProjArgs {
  const unsigned short* Wh;
  const unsigned short* Wl;
  const float* bias;
  unsigned short* outHi;
  unsigned short* outLo;
  float scale;
};

__global__ __launch_bounds__(256) void mfma_proj(
    const unsigned short* __restrict__ Ahi,
    const unsigned short* __restrict__ Alo,
    ProjArgs p0, ProjArgs p1, ProjArgs p2)
{
  __shared__ __align__(16) unsigned short lds[4][4096];  // Ah, Al, Bh, Bl
  const int tid  = threadIdx.x;
  const int lane = tid & 63;
  const int wid  = tid >> 6;
  const int wr   = wid >> 1, wc = wid & 1;
  const int m0   = blockIdx.x * 128, n0 = blockIdx.y * 128;
  const ProjArgs P = (blockIdx.z == 0) ? p0 : ((blockIdx.z == 1) ? p1 : p2);

  const int q0 = tid, q1 = 256 + tid;
  const int row0 = ((q0 >> 5) << 3) | (q0 & 7), kc0 = (q0 >> 3) & 3;
  const int row1 = ((q1 >> 5) << 3) | (q1 & 7), kc1 = (q1 >> 3) & 3;

  const size_t aoff0 = (size_t)(m0 + row0) * 2048 + (size_t)(kc0 * 16);
  const size_t aoff1 = (size_t)(m0 + row1) * 2048 + (size_t)(kc1 * 16);
  const size_t boff0 = (size_t)(n0 + row0) * 2048 + (size_t)(kc0 * 16);
  const size_t boff1 = (size_t)(n0 + row1) * 2048 + (size_t)(kc1 * 16);

  const int dst0 = (wid * 64) * 16;
  const int dst1 = (256 + wid * 64) * 16;

  const char* gAh = (const char*)Ahi;
  const char* gAl = (const char*)Alo;
  const char* gBh = (const char*)P.Wh;
  const char* gBl = (const char*)P.Wl;

  const int fr = lane & 15;
  const int kc = lane >> 4;
  int a_o[4], b_o[4];
  #pragma unroll
  for (int f = 0; f < 4; ++f) {
    int r = wr * 64 + f * 16 + fr;
    a_o[f] = ((r >> 3) << 9) | (kc << 7) | ((r & 7) << 4);
    r = wc * 64 + f * 16 + fr;
    b_o[f] = ((r >> 3) << 9) | (kc << 7) | ((r & 7) << 4);
  }

  f32x4 acc[4][4];
  #pragma unroll
  for (int i = 0; i < 4; ++i)
    #pragma unroll
    for (int j = 0; j < 4; ++j) acc[i][j] = (f32x4){0.f, 0.f, 0.f, 0.f};

  char* L0 = (char*)&lds[0][0];
  char* L1 = (char*)&lds[1][0];
  char* L2 = (char*)&lds[2][0];
  char* L3 = (char*)&lds[3][0];

  for (int ks = 0; ks < 32; ++ks) {
    const size_t kb = (size_t)ks * 64;
    __syncthreads();
    gl_lds16(gAh + aoff0 + kb, L0 + dst0);
    gl_lds16(gAh + aoff1 + kb, L0 + dst1);
    gl_lds16(gAl + aoff0 + kb, L1 + dst0);
    gl_lds16(gAl + aoff1 + kb, L1 + dst1);
    gl_lds16(gBh + boff0 + kb, L2 + dst0);
    gl_lds16(gBh + boff1 + kb, L2 + dst1);
    gl_lds16(gBl + boff0 + kb, L3 + dst0);
    gl_lds16(gBl + boff1 + kb, L3 + dst1);
    __syncthreads();

    bf16x8 ah[4], al[4], bh[4], bl[4];
    #pragma unroll
    for (int f = 0; f < 4; ++f) {
      ah[f] = *(const bf16x8*)(L0 + a_o[f]);
      al[f] = *(const bf16x8*)(L1 + a_o[f]);
      bh[f] = *(const bf16x8*)(L2 + b_o[f]);
      bl[f] = *(const bf16x8*)(L3 + b_o[f]);
    }
    #pragma unroll
    for (int i = 0; i < 4; ++i)
      #pragma unroll
      for (int j = 0; j < 4; ++j)
        acc[i][j] = __builtin_amdgcn_mfma_f32_16x16x32_bf16(ah[i], bh[j], acc[i][j], 0, 0, 0);
    #pragma unroll
    for (int i = 0; i < 4; ++i)
      #pragma unroll
      for (int j = 0; j < 4; ++j)
        acc[i][j] = __builtin_amdgcn_mfma_f32_16x16x32_bf16(ah[i], bl[j], acc[i][j], 0, 0, 0);
    #pragma unroll
    for (int i = 0; i < 4; ++i)
      #pragma unroll
      for (int j = 0; j < 4; ++j)
        acc[i][j] = __builtin_amdgcn_mfma_f32_16x16x32_bf16(al[i], bh[j], acc[i][j], 0, 0, 0);
  }

  const int r4 = (lane >> 4) << 2;
  #pragma unroll
  for (int j = 0; j < 4; ++j) {
    const int col = n0 + wc * 64 + j * 16 + fr;
    const float bv = P.bias[col];
    #pragma unroll
    for (int i = 0; i < 4; ++i) {
      const int rrow = m0 + wr * 64 + i * 16 + r4;
      #pragma unroll
      for (int v = 0; v < 4; ++v) {
        const float val = (acc[i][j][v] + bv) * P.scale;
        const unsigned u = __float_as_uint(val);
        const float r = val - __uint_as_float(u & 0xFFFF0000u);
        unsigned ur = __float_as_uint(r);
        ur += ((ur >> 16) & 1u) + 0x7FFFu;
        const size_t o = (size_t)(rrow + v) * EE + col;
        P.outHi[o] = (unsigned short)(u >> 16);
        P.outLo[o] = (unsigned short)(ur >> 16);
      }
    }
  }
}

// ---------------------------------------------------------------------------
// MFMA fused no-overlap sliding-chunk attention (no inline-asm data path).
// Block = (chunk c, head h, batch b), 4 waves; wave w owns q-rows w*64..+63.
// Per 32-key tile:
//   S^T = mfma(K, Q) 3-pass split    D: q = lane&15, key = (lane>>4)*4+reg
//   online softmax (shfl_xor 16/32), P packed bf16 hi/lo
//   P routed via native-u64 LDS scratch (same-type writes/reads + fence)
//   O^T += mfma(V^T, P^T) 3-pass split; V^T staged in LDS at transposed
//   frag-linear layout via b16 writes with XOR chunk swizzle (bank-spread).
// Zero-padded edge keys folded analytically via nz (exact, as baseline).
// ---------------------------------------------------------------------------
__global__ __launch_bounds__(256, 2) void attn_mfma(
    const unsigned short* __restrict__ Qh_g, const unsigned short* __restrict__ Ql_g,
    const unsigned short* __restrict__ Kh_g, const unsigned short* __restrict__ Kl_g,
    const unsigned short* __restrict__ Vh_g, const unsigned short* __restrict__ Vl_g,
    float* __restrict__ Og)
{
  __shared__ __align__(16) unsigned short Kf[2][2048];   // [plane][frag-linear]
  __shared__ __align__(16) unsigned short Vt[2][2048];   // [plane][V^T frag-linear, swz]
  __shared__ unsigned long long Pscr[4][256];            // per wave: hi[0:128) lo[128:256)

  const int c = blockIdx.x, h = blockIdx.y, b = blockIdx.z;
  const int tid = threadIdx.x;
  const int lane = tid & 63, wid = tid >> 6;
  const int g = lane >> 4, lq = lane & 15;

  const size_t qrow0 = (size_t)(b * NCC + c) * WW;
  const int colh = h * DD;

  // ---- Q B-frags (col q = lane&15, k-elems d = g*8..) ----
  bf16x8 qfh[4][2], qfl[4][2];
  #pragma unroll
  for (int s = 0; s < 4; ++s)
    #pragma unroll
    for (int ch = 0; ch < 2; ++ch) {
      const size_t off = (qrow0 + wid*64 + s*16 + lq) * EE + colh + ch*32 + g*8;
      qfh[s][ch] = *(const bf16x8*)(Qh_g + off);
      qfl[s][ch] = *(const bf16x8*)(Ql_g + off);
    }

  f32x4 Oa[4][4];   // [d-subtile][q-subtile]
  #pragma unroll
  for (int i = 0; i < 4; ++i)
    #pragma unroll
    for (int j = 0; j < 4; ++j) Oa[i][j] = (f32x4){0.f, 0.f, 0.f, 0.f};
  float m[4], lsum[4];
  #pragma unroll
  for (int s = 0; s < 4; ++s) { m[s] = -1e30f; lsum[s] = 0.f; }

  // K staging: wave wid stages A-frag f=wid (kh=wid&1, ch=wid>>1), frag-linear.
  const int kK = 16*(wid & 1) + lq;
  const int dK = 32*(wid >> 1) + g*8;
  // V staging: thread holds V[kV][dV..dV+7]; scattered to V^T frag-linear.
  const int stv = tid >> 5, idxv = tid & 31;
  const int kV = 16*(stv >> 2) + (idxv >> 1);
  const int dV = 16*(stv & 3) + 8*(idxv & 1);
  // V^T layout: elem idx = (d>>4)*512 + (k>>3)*128 + (d&15)*8 + (k&7),
  // chunk = idx>>3, swizzled chunk ^= bits{6,4,3} of chunk (bank spread).
  const int C0  = ((dV >> 4) << 6) | ((kV >> 3) << 4) | (dV & 15);  // C0&7==0
  const int swW = (((dV >> 4) & 1) << 2) | (((kV >> 3) & 1) << 1) | ((dV >> 3) & 1);
  const int vel = kV & 7;

  const long krow0_base = (long)qrow0 - WW;
  const int t0 = (c == 0) ? 8 : 0;
  const int tN = (c == NCC-1) ? 16 : 24;

  uint4 rkh, rkl, rvh, rvl;
  {
    const long kr = krow0_base + (long)t0*32;
    const size_t offK = (size_t)(kr + kK) * EE + colh + dK;
    const size_t offV = (size_t)(kr + kV) * EE + colh + dV;
    rkh = *(const uint4*)(Kh_g + offK); rkl = *(const uint4*)(Kl_g + offK);
    rvh = *(const uint4*)(Vh_g + offV); rvl = *(const uint4*)(Vl_g + offV);
  }

  for (int tt = t0; tt < tN; ++tt) {
    __syncthreads();   // all waves done reading previous tile's Kf/Vt
    *(uint4*)&Kf[0][wid*512 + lane*8] = rkh;
    *(uint4*)&Kf[1][wid*512 + lane*8] = rkl;
    {
      const unsigned hw[4] = {rvh.x, rvh.y, rvh.z, rvh.w};
      const unsigned lw[4] = {rvl.x, rvl.y, rvl.z, rvl.w};
      #pragma unroll
      for (int t = 0; t < 8; ++t) {
        const int ii = C0*8 + ((t ^ swW) << 3) + vel;
        Vt[0][ii] = (unsigned short)(hw[t >> 1] >> ((t & 1) * 16));
        Vt[1][ii] = (unsigned short)(lw[t >> 1] >> ((t & 1) * 16));
      }
    }
    __syncthreads();   // tile ready

    if (tt + 1 < tN) {   // issue next tile's loads early (hide HBM latency)
      const long kr = krow0_base + (long)(tt+1)*32;
      const size_t offK = (size_t)(kr + kK) * EE + colh + dK;
      const size_t offV = (size_t)(kr + kV) * EE + colh + dV;
      rkh = *(const uint4*)(Kh_g + offK); rkl = *(const uint4*)(Kl_g + offK);
      rvh = *(const uint4*)(Vh_g + offV); rvl = *(const uint4*)(Vl_g + offV);
    }

    // K A-frags: contiguous wave-wide ds_read_b128
    bf16x8 kfh[2][2], kfl[2][2];
    #pragma unroll
    for (int f = 0; f < 4; ++f) {
      const int o = f*512 + lane*8;
      kfh[f & 1][f >> 1] = *(const bf16x8*)&Kf[0][o];
      kfl[f & 1][f >> 1] = *(const bf16x8*)&Kf[1][o];
    }

    // V^T A-frags: contiguous b128 with matching XOR chunk swizzle.
    // vf[ds][e] = V[k = g*8+e][d = ds*16+lq]
    bf16x8 vfh[4], vfl[4];
    #pragma unroll
    for (int ds = 0; ds < 4; ++ds) {
      const int rch = ds*64 + g*16 + lq;
      const int rsw = (((rch >> 6) & 1) << 2) | (((rch >> 4) & 1) << 1) | ((rch >> 3) & 1);
      vfh[ds] = *(const bf16x8*)&Vt[0][(rch ^ rsw) * 8];
      vfl[ds] = *(const bf16x8*)&Vt[1][(rch ^ rsw) * 8];
    }

    #pragma unroll
    for (int s = 0; s < 4; ++s) {
      // ---- QK^T (3-pass split), D: col q = lane&15, key = g*4 + reg ----
      f32x4 ac0 = (f32x4){0.f,0.f,0.f,0.f}, ac1 = (f32x4){0.f,0.f,0.f,0.f};
      #pragma unroll
      for (int ch = 0; ch < 2; ++ch) {
        ac0 = __builtin_amdgcn_mfma_f32_16x16x32_bf16(kfh[0][ch], qfh[s][ch], ac0, 0,0,0);
        ac0 = __builtin_amdgcn_mfma_f32_16x16x32_bf16(kfh[0][ch], qfl[s][ch], ac0, 0,0,0);
        ac0 = __builtin_amdgcn_mfma_f32_16x16x32_bf16(kfl[0][ch], qfh[s][ch], ac0, 0,0,0);
        ac1 = __builtin_amdgcn_mfma_f32_16x16x32_bf16(kfh[1][ch], qfh[s][ch], ac1, 0,0,0);
        ac1 = __builtin_amdgcn_mfma_f32_16x16x32_bf16(kfh[1][ch], qfl[s][ch], ac1, 0,0,0);
        ac1 = __builtin_amdgcn_mfma_f32_16x16x32_bf16(kfl[1][ch], qfh[s][ch], ac1, 0,0,0);
      }

      // ---- online softmax (per q-column, reduce over the 4 g-lanes) ----
      float tmax = fmaxf(fmaxf(fmaxf(ac0[0],ac0[1]), fmaxf(ac0[2],ac0[3])),
                         fmaxf(fmaxf(ac1[0],ac1[1]), fmaxf(ac1[2],ac1[3])));
      tmax = fmaxf(tmax, __shfl_xor(tmax, 16));
      tmax = fmaxf(tmax, __shfl_xor(tmax, 32));
      const float mo = m[s];
      const float mn = fmaxf(mo, tmax);
      m[s] = mn;
      const float sc = __expf(mo - mn);   // exp(-1e30 - x) == 0
      float pv[8];
      #pragma unroll
      for (int r = 0; r < 4; ++r) { pv[r] = __expf(ac0[r] - mn); pv[4+r] = __expf(ac1[r] - mn); }
      float ps = 0.f;
      #pragma unroll
      for (int r = 0; r < 8; ++r) ps += pv[r];
      lsum[s] = lsum[s] * sc + ps;
      #pragma unroll
      for (int ds = 0; ds < 4; ++ds) Oa[ds][s] *= sc;

      // ---- pack P hi/lo, route via native-u64 LDS scratch ----
      unsigned hb[8], lb[8];
      #pragma unroll
      for (int r = 0; r < 8; ++r) {
        hb[r] = bf16rne(pv[r]);
        const float rr = pv[r] - __uint_as_float(hb[r] << 16);
        lb[r] = bf16rne(rr);
      }
      const int pq = (g >> 1)*32 + lq*2 + (g & 1);   // u64 index; *4 = short idx
      Pscr[wid][pq]            = pack64(hb[0],hb[1],hb[2],hb[3]);
      Pscr[wid][pq + 64]       = pack64(hb[4],hb[5],hb[6],hb[7]);
      Pscr[wid][128 + pq]      = pack64(lb[0],lb[1],lb[2],lb[3]);
      Pscr[wid][128 + pq + 64] = pack64(lb[4],lb[5],lb[6],lb[7]);
      asm volatile("" ::: "memory");   // compiler fence: writes before reads
      union U8 { unsigned long long q[2]; bf16x8 v; };
      U8 uh, ul;
      uh.q[0] = Pscr[wid][lane*2];       uh.q[1] = Pscr[wid][lane*2 + 1];
      ul.q[0] = Pscr[wid][128 + lane*2]; ul.q[1] = Pscr[wid][128 + lane*2 + 1];
      const bf16x8 pbh = uh.v;
      const bf16x8 pbl = ul.v;

      // ---- PV (3-pass split): O^T[d][q] += V^T · P^T ----
      #pragma unroll
      for (int ds = 0; ds < 4; ++ds) {
        Oa[ds][s] = __builtin_amdgcn_mfma_f32_16x16x32_bf16(vfh[ds], pbh, Oa[ds][s], 0,0,0);
        Oa[ds][s] = __builtin_amdgcn_mfma_f32_16x16x32_bf16(vfl[ds], pbh, Oa[ds][s], 0,0,0);
        Oa[ds][s] = __builtin_amdgcn_mfma_f32_16x16x32_bf16(vfh[ds], pbl, Oa[ds][s], 0,0,0);
      }
    }
  }

  // ---- epilogue: fold zero-pad keys, normalize, store ----
  #pragma unroll
  for (int s = 0; s < 4; ++s) {
    float ls = lsum[s];
    ls += __shfl_xor(ls, 16);
    ls += __shfl_xor(ls, 32);
    const int x = wid*64 + s*16 + lq;
    const float nz = (c == 0) ? (float)x
                   : ((c == NCC-1) ? (float)(WW - 1 - x) : 0.f);
    ls += nz * __expf(0.f - m[s]);
    const float inv = 1.f / ls;
    float* op = Og + (qrow0 + x) * EE + colh;
    #pragma unroll
    for (int ds = 0; ds < 4; ++ds) {
      float4 r;
      r.x = Oa[ds][s][0]*inv; r.y = Oa[ds][s][1]*inv;
      r.z = Oa[ds][s][2]*inv; r.w = Oa[ds][s][3]*inv;
      *(float4*)(op + ds*16 + g*4) = r;
    }
  }
}

extern "C" void kernel_launch(void* const* d_in, const int* in_sizes, int n_in,
                              void* d_out, int out_size, void* d_ws, size_t ws_size,
                              hipStream_t stream) {
    const float* hs = (const float*)d_in[0];
    const float* Wq = (const float*)d_in[1];
    const float* bq = (const float*)d_in[2];
    const float* Wk = (const float*)d_in[3];
    const float* bk = (const float*)d_in[4];
    const float* Wv = (const float*)d_in[5];
    const float* bv = (const float*)d_in[6];
    float* out = (float*)d_out;

    const size_t mat  = (size_t)MTOT * EE;   // 8388608
    const size_t wmat = (size_t)EE * EE;     // 1048576

    unsigned short* w = (unsigned short*)d_ws;
    unsigned short* Ahi = w;            unsigned short* Alo = Ahi + mat;
    unsigned short* Wqh = Alo + mat;    unsigned short* Wql = Wqh + wmat;
    unsigned short* Wkh = Wql + wmat;   unsigned short* Wkl = Wkh + wmat;
    unsigned short* Wvh = Wkl + wmat;   unsigned short* Wvl = Wvh + wmat;
    unsigned short* Qhb = Wvl + wmat;   unsigned short* Qlb = Qhb + mat;
    unsigned short* Khb = Qlb + mat;    unsigned short* Klb = Khb + mat;
    unsigned short* Vhb = Klb + mat;    unsigned short* Vlb = Vhb + mat;
    // total ws: (8*mat + 6*wmat)*2B = 140 MB (same budget as the passing R1)

    split_kernel<<<(mat/4)/256,  256, 0, stream>>>(hs, Ahi, Alo);
    split_kernel<<<(wmat/4)/256, 256, 0, stream>>>(Wq, Wqh, Wql);
    split_kernel<<<(wmat/4)/256, 256, 0, stream>>>(Wk, Wkh, Wkl);
    split_kernel<<<(wmat/4)/256, 256, 0, stream>>>(Wv, Wvh, Wvl);

    ProjArgs pq{Wqh, Wql, bq, Qhb, Qlb, 0.125f};   // 1/sqrt(64)
    ProjArgs pk{Wkh, Wkl, bk, Khb, Klb, 1.0f};
    ProjArgs pv{Wvh, Wvl, bv, Vhb, Vlb, 1.0f};
    dim3 g(MTOT/128, EE/128, 3);
    mfma_proj<<<g, 256, 0, stream>>>(Ahi, Alo, pq, pk, pv);

    dim3 ga(NCC, HH, BB);
    attn_mfma<<<ga, 256, 0, stream>>>(Qhb, Qlb, Khb, Klb, Vhb, Vlb, out);
}